// Round 10
// baseline (70.184 us; speedup 1.0000x reference)
//
#include <hip/hip_runtime.h>
#include <hip/hip_bf16.h>

#define NB 8
#define SEQ 2048
#define HD 1024
#define DK 64

// exp2-domain constants: Q pre-scaled by 0.125/ln2, fixed softmax base 8/ln2
#define QSCALE 0.1803368801111244f
#define FIXMAX2 11.541560327111708f

typedef __attribute__((ext_vector_type(4))) float f32x4;
typedef __attribute__((ext_vector_type(8))) short bf16x8;
typedef __attribute__((ext_vector_type(4))) unsigned short u16x4;

// raw barrier: LDS-only fence (lgkmcnt), NO vmcnt drain -> global loads stay in flight
#define LDS_BARRIER() asm volatile("s_waitcnt lgkmcnt(0)\n\ts_barrier" ::: "memory")

__device__ __forceinline__ short f2bf(float f) {
    union { float f; unsigned u; } v; v.f = f;
    unsigned r = v.u + 0x7fffu + ((v.u >> 16) & 1u);
    return (short)(r >> 16);
}
__device__ __forceinline__ bf16x8 pack8(f32x4 v0, f32x4 v1) {
    union { bf16x8 v; __hip_bfloat162 h[4]; } u;
    u.h[0] = __float22bfloat162_rn(make_float2(v0[0], v0[1]));
    u.h[1] = __float22bfloat162_rn(make_float2(v0[2], v0[3]));
    u.h[2] = __float22bfloat162_rn(make_float2(v1[0], v1[1]));
    u.h[3] = __float22bfloat162_rn(make_float2(v1[2], v1[3]));
    return u.v;
}

// ---------------- prep: W pack (blocks 0..767) + lengths (768..775) ----------------
// Wp2[(((kbg*4+cg)*2+kh)*3+fr)*512 + lane*8 + j] = W_m[k][colm]
__global__ void prep_kernel(const unsigned* __restrict__ mask,
                            const float* __restrict__ Wq, const float* __restrict__ Wk,
                            const float* __restrict__ Wv,
                            int* __restrict__ lengths, short* __restrict__ Wp) {
    if (blockIdx.x < 768) {
        int idx = blockIdx.x * 256 + threadIdx.x;     // 0..196607
        int j = idx & 7, lane = (idx >> 3) & 63;
        int slot = idx >> 9;                          // 0..383
        int fr = slot % 3, q2 = slot / 3;
        int kh = q2 & 1, cg = (q2 >> 1) & 3, kbg = q2 >> 3;
        int g = lane >> 4, c = lane & 15;
        int n = cg * 3 + fr;
        int m = n >> 2, colm = (n & 3) * 16 + c;
        int k = kbg * 64 + kh * 32 + g * 8 + j;
        const float* W = (m == 0) ? Wq : (m == 1) ? Wk : Wv;
        Wp[idx] = f2bf(W[(size_t)k * DK + colm]);
        return;
    }
    __shared__ int sdet;
    __shared__ int scnt;
    int b = blockIdx.x - 768, t = threadIdx.x;
    if (t == 0) { sdet = 0; scnt = 0; }
    __syncthreads();
    int det = 0;
    for (int i = t; i < 4096; i += 256) {
        unsigned w = mask[i];
        if (w > 1u && w != 0x3F800000u) det = 1;
    }
    if (det) atomicOr(&sdet, 1);
    __syncthreads();
    int cnt = 0;
    if (sdet) {
        const unsigned char* m8 = (const unsigned char*)mask;
        for (int s = t; s < SEQ; s += 256) cnt += (m8[b * SEQ + s] == 0) ? 1 : 0;
    } else {
        for (int s = t; s < SEQ; s += 256) cnt += (mask[b * SEQ + s] == 0u) ? 1 : 0;
    }
    atomicAdd(&scnt, cnt);
    __syncthreads();
    if (t == 0) lengths[b] = scnt;
}

// ---------------- QKV v10: dbuf-LDS GEMM, counted-vmcnt pipeline ----------------
// Identical to v9 EXCEPT the barrier: raw s_barrier with lgkmcnt(0) only.
// The 2-step-ahead x loads now survive the barrier; the only vmcnt wait is the
// compiler's counted wait at the ds_write use-point (~2 K-steps after issue).
__global__ __launch_bounds__(256) void qkv_kernel(
    const float* __restrict__ x,
    const float* __restrict__ bq, const float* __restrict__ bk, const float* __restrict__ bv,
    const short* __restrict__ Wp,
    short* __restrict__ Q, short* __restrict__ K, short* __restrict__ Vt) {
    __shared__ float xs[2][32][64];    // 16 KiB, granule-swizzled
    int t = threadIdx.x;
    int cg = t >> 6, lane = t & 63;
    int g = lane >> 4, c = lane & 15;
    int r0 = blockIdx.x * 32;
    int bb = r0 >> 11, sbase = r0 & (SEQ - 1);

    int srow = t >> 3, sc8 = t & 7;
    const float* xsrc = x + (size_t)(r0 + srow) * HD + sc8 * 8;
    float* wbase = &xs[0][0][0];
    int wo0 = srow * 64 + (((2 * sc8) ^ (srow & 15)) << 2);
    int wo1 = srow * 64 + (((2 * sc8 + 1) ^ (srow & 15)) << 2);

    const short* wpw = Wp + (size_t)cg * 3072 + (size_t)lane * 8;

    f32x4 z = {0.f, 0.f, 0.f, 0.f};
    f32x4 acc[2][3];
    #pragma unroll
    for (int rf = 0; rf < 2; rf++)
        #pragma unroll
        for (int fr = 0; fr < 3; fr++) acc[rf][fr] = z;

    // prologue: stage step 0, preload B step 0, issue x step 1
    {
        f32x4 x0 = *(const f32x4*)xsrc;
        f32x4 x1 = *(const f32x4*)(xsrc + 4);
        *(f32x4*)(wbase + wo0) = x0;
        *(f32x4*)(wbase + wo1) = x1;
    }
    bf16x8 Bc[2][3];
    #pragma unroll
    for (int kh = 0; kh < 2; kh++)
        #pragma unroll
        for (int fr = 0; fr < 3; fr++)
            Bc[kh][fr] = *(const bf16x8*)(wpw + kh * 1536 + fr * 512);
    f32x4 nxA0 = *(const f32x4*)(xsrc + 64);
    f32x4 nxA1 = *(const f32x4*)(xsrc + 68);
    LDS_BARRIER();

    const float* rbase0 = &xs[0][0][0] + c * 64;   // + cur*2048 + rf*1024
    #pragma unroll
    for (int kbg = 0; kbg < 16; kbg++) {
        int cur = kbg & 1;
        // issue x loads for kbg+2 (2-deep) and B loads for kbg+1 (1-deep) FIRST
        f32x4 nxB0, nxB1;
        bf16x8 Bn[2][3];
        if (kbg < 14) {
            const float* p = xsrc + (kbg + 2) * 64;
            nxB0 = *(const f32x4*)p;
            nxB1 = *(const f32x4*)(p + 4);
        }
        if (kbg < 15) {
            #pragma unroll
            for (int kh = 0; kh < 2; kh++)
                #pragma unroll
                for (int fr = 0; fr < 3; fr++)
                    Bn[kh][fr] = *(const bf16x8*)(wpw + (kbg + 1) * 12288 + kh * 1536 + fr * 512);
        }
        // A frags from swizzled LDS (f32 -> bf16)
        bf16x8 Af[2][2];
        #pragma unroll
        for (int rf = 0; rf < 2; rf++)
            #pragma unroll
            for (int kh = 0; kh < 2; kh++) {
                const float* rp = rbase0 + cur * 2048 + rf * 1024;
                int lg = kh * 8 + 2 * g;
                f32x4 lo = *(const f32x4*)(rp + ((lg ^ c) << 2));
                f32x4 hi = *(const f32x4*)(rp + (((lg + 1) ^ c) << 2));
                Af[rf][kh] = pack8(lo, hi);
            }
        #pragma unroll
        for (int kh = 0; kh < 2; kh++)
            #pragma unroll
            for (int fr = 0; fr < 3; fr++)
                #pragma unroll
                for (int rf = 0; rf < 2; rf++)
                    acc[rf][fr] = __builtin_amdgcn_mfma_f32_16x16x32_bf16(Af[rf][kh], Bc[kh][fr], acc[rf][fr], 0, 0, 0);
        if (kbg < 15) {
            float* wb = wbase + (cur ^ 1) * 2048;
            *(f32x4*)(wb + wo0) = nxA0;     // counted vmcnt wait here (loads 1 step old)
            *(f32x4*)(wb + wo1) = nxA1;
            #pragma unroll
            for (int kh = 0; kh < 2; kh++)
                #pragma unroll
                for (int fr = 0; fr < 3; fr++) Bc[kh][fr] = Bn[kh][fr];
        }
        if (kbg < 14) { nxA0 = nxB0; nxA1 = nxB1; }
        LDS_BARRIER();
    }

    // epilogue
    #pragma unroll
    for (int rf = 0; rf < 2; rf++)
        #pragma unroll
        for (int fr = 0; fr < 3; fr++) {
            int n = cg * 3 + fr;
            int m = n >> 2, colm = (n & 3) * 16 + c;
            const float* bias = (m == 0) ? bq : (m == 1) ? bk : bv;
            float bv_ = bias[colm];
            if (m == 2) {
                u16x4 pk;
                #pragma unroll
                for (int j = 0; j < 4; j++) pk[j] = (unsigned short)f2bf(acc[rf][fr][j] + bv_);
                int srw = sbase + rf * 16 + 4 * g;
                *(u16x4*)(Vt + (size_t)bb * DK * SEQ + (size_t)colm * SEQ + srw) = pk;
            } else {
                #pragma unroll
                for (int j = 0; j < 4; j++) {
                    int row = r0 + rf * 16 + 4 * g + j;
                    float s = acc[rf][fr][j] + bv_;
                    if (m == 0) Q[(size_t)row * DK + colm] = f2bf(s * QSCALE);
                    else        K[(size_t)row * DK + colm] = f2bf(s);
                }
            }
        }
}

// ---------------- flash attention v10: 16-row q-tiles, grid 1024, 4 waves ----------
// Block = one 16-row q-tile, 4 waves on interleaved 64-key stripes.
// 4 blocks/CU resident -> ~16 waves/CU (2x TLP vs 32-row/512-block version).
__global__ __launch_bounds__(256) void attn_kernel(
    const short* __restrict__ Q, const short* __restrict__ K_, const short* __restrict__ Vt,
    const int* __restrict__ lengths, float* __restrict__ out) {
    __shared__ float macc[4][16][66];          // merge buffer (16.9 KiB)
    __shared__ float ll[4][16];
    short* plds = (short*)&macc[0][0][0];      // aliased P-transpose region (9 KiB)

    int bid = blockIdx.x;
    int qt = 127 - (bid & 127);                // heavy tiles dispatch first
    int b = bid >> 7;
    int len = lengths[b];
    int qbase = qt * 16;
    int t = threadIdx.x;
    int w = t >> 6, lane = t & 63;
    int g = lane >> 4, c = lane & 15;

    if (qbase >= len) {                        // fully padded tile -> zeros
        int row = t >> 4, col0 = (t & 15) * 4;
        f32x4 zz = {0.f, 0.f, 0.f, 0.f};
        *(f32x4*)(out + ((size_t)b * SEQ + qbase + row) * DK + col0) = zz;
        return;
    }

    int kend = min(len, qbase + 16);
    int ntiles = (kend + 63) >> 6;
    const short* Qb = Q + ((size_t)b * SEQ + qbase) * DK;
    const short* Kb = K_ + (size_t)b * SEQ * DK;
    const short* Vb = Vt + (size_t)b * DK * SEQ;

    bf16x8 qa[2];
    #pragma unroll
    for (int kh = 0; kh < 2; kh++)
        qa[kh] = *(const bf16x8*)(Qb + c * DK + kh * 32 + g * 8);

    int rowcap[4];
    #pragma unroll
    for (int j = 0; j < 4; j++)
        rowcap[j] = min(qbase + 4 * g + j, len - 1);

    f32x4 z = {0.f, 0.f, 0.f, 0.f};
    f32x4 acc[4];
    float l_r[4];
    #pragma unroll
    for (int n = 0; n < 4; n++) acc[n] = z;
    #pragma unroll
    for (int j = 0; j < 4; j++) l_r[j] = 0.f;

    short* pldsw = plds + w * 1120;            // [16][70] shorts per wave

    for (int tt = w; tt < ntiles; tt += 4) {
        int kb = tt * 64;
        // all K loads for this tile (4 x 16 keys)
        bf16x8 kr[4][2];
        #pragma unroll
        for (int kt = 0; kt < 4; kt++) {
            const short* kp = Kb + (size_t)(kb + kt * 16 + c) * DK + g * 8;
            kr[kt][0] = *(const bf16x8*)kp;
            kr[kt][1] = *(const bf16x8*)(kp + 32);
        }
        // QK^T
        f32x4 sf[4];
        #pragma unroll
        for (int kt = 0; kt < 4; kt++) {
            f32x4 t0 = __builtin_amdgcn_mfma_f32_16x16x32_bf16(qa[0], kr[kt][0], z, 0, 0, 0);
            sf[kt] = __builtin_amdgcn_mfma_f32_16x16x32_bf16(qa[1], kr[kt][1], t0, 0, 0, 0);
        }
        // V loads (in flight during softmax)
        bf16x8 vr[4][2];
        #pragma unroll
        for (int n = 0; n < 4; n++) {
            const short* vp = Vb + (size_t)(n * 16 + c) * SEQ + kb + g * 8;
            vr[n][0] = *(const bf16x8*)vp;
            vr[n][1] = *(const bf16x8*)(vp + 32);
        }
        // mask + exp2 + per-lane l accumulation (no cross-lane ops)
        #pragma unroll
        for (int kt = 0; kt < 4; kt++) {
            int key = kb + kt * 16 + c;
            #pragma unroll
            for (int j = 0; j < 4; j++) {
                float s = (key > rowcap[j]) ? -1e30f : sf[kt][j];
                float p = exp2f(s - FIXMAX2);
                sf[kt][j] = p;
                l_r[j] += p;
            }
        }
        // P: D-layout -> LDS -> A-layout (wave-private lockstep, no barrier)
        #pragma unroll
        for (int kt = 0; kt < 4; kt++)
            #pragma unroll
            for (int j = 0; j < 4; j++)
                pldsw[(4 * g + j) * 70 + kt * 16 + c] = f2bf(sf[kt][j]);
        bf16x8 pa0 = *(const bf16x8*)(pldsw + c * 70 + g * 8);
        bf16x8 pa1 = *(const bf16x8*)(pldsw + c * 70 + 32 + g * 8);
        #pragma unroll
        for (int n = 0; n < 4; n++) {
            acc[n] = __builtin_amdgcn_mfma_f32_16x16x32_bf16(pa0, vr[n][0], acc[n], 0, 0, 0);
            acc[n] = __builtin_amdgcn_mfma_f32_16x16x32_bf16(pa1, vr[n][1], acc[n], 0, 0, 0);
        }
    }

    // one-time l reduction across the 16 lanes holding each row
    #pragma unroll
    for (int d = 1; d < 16; d <<= 1)
        #pragma unroll
        for (int j = 0; j < 4; j++) l_r[j] += __shfl_xor(l_r[j], d);

    __syncthreads();   // plds lifetime over -> reuse as macc
    #pragma unroll
    for (int n = 0; n < 4; n++)
        #pragma unroll
        for (int j = 0; j < 4; j++)
            macc[w][4 * g + j][n * 16 + c] = acc[n][j];
    if (c == 0) {
        #pragma unroll
        for (int j = 0; j < 4; j++)
            ll[w][4 * g + j] = l_r[j];
    }
    __syncthreads();
    // merge: plain sums (all waves share the same fixed max)
    {
        int row = t >> 4, seg = t & 15;
        int r = qbase + row;
        float* op = out + ((size_t)b * SEQ + r) * DK + seg * 4;
        float o[4] = {0.f, 0.f, 0.f, 0.f};
        if (r < len) {
            float L = ll[0][row] + ll[1][row] + ll[2][row] + ll[3][row];
            #pragma unroll
            for (int wv = 0; wv < 4; wv++)
                #pragma unroll
                for (int i = 0; i < 4; i++) o[i] += macc[wv][row][seg * 4 + i];
            float inv = 1.f / L;
            #pragma unroll
            for (int i = 0; i < 4; i++) o[i] *= inv;
        }
        #pragma unroll
        for (int i = 0; i < 4; i++) op[i] = o[i];
    }
}

extern "C" void kernel_launch(void* const* d_in, const int* in_sizes, int n_in,
                              void* d_out, int out_size, void* d_ws, size_t ws_size,
                              hipStream_t stream) {
    const float* x  = (const float*)d_in[0];
    const unsigned* mask = (const unsigned*)d_in[1];
    const float* Wq = (const float*)d_in[2];
    const float* bq = (const float*)d_in[3];
    const float* Wk = (const float*)d_in[4];
    const float* bk = (const float*)d_in[5];
    const float* Wv = (const float*)d_in[6];
    const float* bv = (const float*)d_in[7];
    float* out = (float*)d_out;

    char* ws = (char*)d_ws;
    int*   lengths = (int*)ws;                          // 256 B
    short* Wp = (short*)(ws + 256);                     // 384 KiB (Wp2 layout)
    short* Q  = (short*)(ws + 393472);                  // 2 MiB
    short* K  = (short*)(ws + 2490624);                 // 2 MiB
    short* Vt = (short*)(ws + 4587776);                 // 2 MiB

    hipLaunchKernelGGL(prep_kernel, dim3(776), dim3(256), 0, stream, mask, Wq, Wk, Wv, lengths, Wp);
    hipLaunchKernelGGL(qkv_kernel, dim3(512), dim3(256), 0, stream,
                       x, bq, bk, bv, Wp, Q, K, Vt);
    hipLaunchKernelGGL(attn_kernel, dim3(NB * 128), dim3(256), 0, stream,
                       Q, K, Vt, lengths, out);
}

// Round 11
// 58.056 us; speedup vs baseline: 1.2089x; 1.2089x over previous
//
#include <hip/hip_runtime.h>
#include <hip/hip_bf16.h>

#define NB 8
#define SEQ 2048
#define HD 1024
#define DK 64

// exp2-domain constants: Q pre-scaled by 0.125/ln2, fixed softmax base 8/ln2
#define QSCALE 0.1803368801111244f
#define FIXMAX2 11.541560327111708f

typedef __attribute__((ext_vector_type(4))) float f32x4;
typedef __attribute__((ext_vector_type(8))) short bf16x8;
typedef __attribute__((ext_vector_type(4))) unsigned short u16x4;

// raw barrier: LDS-only fence (lgkmcnt), NO vmcnt drain -> global loads stay in flight
#define LDS_BARRIER() asm volatile("s_waitcnt lgkmcnt(0)\n\ts_barrier" ::: "memory")

__device__ __forceinline__ short f2bf(float f) {
    union { float f; unsigned u; } v; v.f = f;
    unsigned r = v.u + 0x7fffu + ((v.u >> 16) & 1u);
    return (short)(r >> 16);
}
__device__ __forceinline__ bf16x8 pack8(f32x4 v0, f32x4 v1) {
    union { bf16x8 v; __hip_bfloat162 h[4]; } u;
    u.h[0] = __float22bfloat162_rn(make_float2(v0[0], v0[1]));
    u.h[1] = __float22bfloat162_rn(make_float2(v0[2], v0[3]));
    u.h[2] = __float22bfloat162_rn(make_float2(v1[0], v1[1]));
    u.h[3] = __float22bfloat162_rn(make_float2(v1[2], v1[3]));
    return u.v;
}

// ---------------- prep: W pack (blocks 0..767) + lengths (768..775) ----------------
// Wp2[(((kbg*4+cg)*2+kh)*3+fr)*512 + lane*8 + j] = W_m[k][colm]
__global__ void prep_kernel(const unsigned* __restrict__ mask,
                            const float* __restrict__ Wq, const float* __restrict__ Wk,
                            const float* __restrict__ Wv,
                            int* __restrict__ lengths, short* __restrict__ Wp) {
    if (blockIdx.x < 768) {
        int idx = blockIdx.x * 256 + threadIdx.x;     // 0..196607
        int j = idx & 7, lane = (idx >> 3) & 63;
        int slot = idx >> 9;                          // 0..383
        int fr = slot % 3, q2 = slot / 3;
        int kh = q2 & 1, cg = (q2 >> 1) & 3, kbg = q2 >> 3;
        int g = lane >> 4, c = lane & 15;
        int n = cg * 3 + fr;
        int m = n >> 2, colm = (n & 3) * 16 + c;
        int k = kbg * 64 + kh * 32 + g * 8 + j;
        const float* W = (m == 0) ? Wq : (m == 1) ? Wk : Wv;
        Wp[idx] = f2bf(W[(size_t)k * DK + colm]);
        return;
    }
    __shared__ int sdet;
    __shared__ int scnt;
    int b = blockIdx.x - 768, t = threadIdx.x;
    if (t == 0) { sdet = 0; scnt = 0; }
    __syncthreads();
    int det = 0;
    for (int i = t; i < 4096; i += 256) {
        unsigned w = mask[i];
        if (w > 1u && w != 0x3F800000u) det = 1;
    }
    if (det) atomicOr(&sdet, 1);
    __syncthreads();
    int cnt = 0;
    if (sdet) {
        const unsigned char* m8 = (const unsigned char*)mask;
        for (int s = t; s < SEQ; s += 256) cnt += (m8[b * SEQ + s] == 0) ? 1 : 0;
    } else {
        for (int s = t; s < SEQ; s += 256) cnt += (mask[b * SEQ + s] == 0u) ? 1 : 0;
    }
    atomicAdd(&scnt, cnt);
    __syncthreads();
    if (t == 0) lengths[b] = scnt;
}

// ---------------- QKV v11: bf16-in-LDS dbuf GEMM, counted-vmcnt pipeline -----------
// x converted f32->bf16 ONCE at staging (kills 4x redundant per-wave conversion);
// LDS 8 KiB; reads are direct ds_read_b128 bf16 fragments via 16B-granule XOR swizzle.
__global__ __launch_bounds__(256) void qkv_kernel(
    const float* __restrict__ x,
    const float* __restrict__ bq, const float* __restrict__ bk, const float* __restrict__ bv,
    const short* __restrict__ Wp,
    short* __restrict__ Q, short* __restrict__ K, short* __restrict__ Vt) {
    __shared__ short xs[2][32][64];    // 8 KiB bf16, granule-swizzled
    int t = threadIdx.x;
    int cg = t >> 6, lane = t & 63;
    int g = lane >> 4, c = lane & 15;
    int r0 = blockIdx.x * 32;
    int bb = r0 >> 11, sbase = r0 & (SEQ - 1);

    // staging map: thread t -> row (t>>3), 16B bf16 chunk (t&7)
    int srow = t >> 3, ch = t & 7;
    const float* xsrc = x + (size_t)(r0 + srow) * HD + ch * 8;
    short* wbase = &xs[0][0][0];
    int wo = srow * 64 + ((ch ^ (srow & 7)) << 3);    // shorts

    const short* wpw = Wp + (size_t)cg * 3072 + (size_t)lane * 8;

    f32x4 z = {0.f, 0.f, 0.f, 0.f};
    f32x4 acc[2][3];
    #pragma unroll
    for (int rf = 0; rf < 2; rf++)
        #pragma unroll
        for (int fr = 0; fr < 3; fr++) acc[rf][fr] = z;

    // prologue: stage step 0 (convert at write), preload B step 0, issue x step 1
    {
        f32x4 x0 = *(const f32x4*)xsrc;
        f32x4 x1 = *(const f32x4*)(xsrc + 4);
        *(bf16x8*)(wbase + wo) = pack8(x0, x1);
    }
    bf16x8 Bc[2][3];
    #pragma unroll
    for (int kh = 0; kh < 2; kh++)
        #pragma unroll
        for (int fr = 0; fr < 3; fr++)
            Bc[kh][fr] = *(const bf16x8*)(wpw + kh * 1536 + fr * 512);
    f32x4 nxA0 = *(const f32x4*)(xsrc + 64);
    f32x4 nxA1 = *(const f32x4*)(xsrc + 68);
    LDS_BARRIER();

    const short* rbase0 = &xs[0][0][0] + c * 64;   // + cur*2048 + rf*1024 + chunk*8
    #pragma unroll
    for (int kbg = 0; kbg < 16; kbg++) {
        int cur = kbg & 1;
        // issue x loads for kbg+2 (2-deep) and B loads for kbg+1 (1-deep) FIRST
        f32x4 nxB0, nxB1;
        bf16x8 Bn[2][3];
        if (kbg < 14) {
            const float* p = xsrc + (kbg + 2) * 64;
            nxB0 = *(const f32x4*)p;
            nxB1 = *(const f32x4*)(p + 4);
        }
        if (kbg < 15) {
            #pragma unroll
            for (int kh = 0; kh < 2; kh++)
                #pragma unroll
                for (int fr = 0; fr < 3; fr++)
                    Bn[kh][fr] = *(const bf16x8*)(wpw + (kbg + 1) * 12288 + kh * 1536 + fr * 512);
        }
        // A frags: direct bf16 ds_read_b128 (no conversion)
        bf16x8 Af[2][2];
        #pragma unroll
        for (int rf = 0; rf < 2; rf++)
            #pragma unroll
            for (int kh = 0; kh < 2; kh++)
                Af[rf][kh] = *(const bf16x8*)(rbase0 + cur * 2048 + rf * 1024
                                              + (((kh * 4 + g) ^ (c & 7)) << 3));
        #pragma unroll
        for (int kh = 0; kh < 2; kh++)
            #pragma unroll
            for (int fr = 0; fr < 3; fr++)
                #pragma unroll
                for (int rf = 0; rf < 2; rf++)
                    acc[rf][fr] = __builtin_amdgcn_mfma_f32_16x16x32_bf16(Af[rf][kh], Bc[kh][fr], acc[rf][fr], 0, 0, 0);
        if (kbg < 15) {
            // counted vmcnt wait lands here (nxA issued 2 steps ago)
            *(bf16x8*)(wbase + (cur ^ 1) * 2048 + wo) = pack8(nxA0, nxA1);
            #pragma unroll
            for (int kh = 0; kh < 2; kh++)
                #pragma unroll
                for (int fr = 0; fr < 3; fr++) Bc[kh][fr] = Bn[kh][fr];
        }
        if (kbg < 14) { nxA0 = nxB0; nxA1 = nxB1; }
        LDS_BARRIER();
    }

    // epilogue
    #pragma unroll
    for (int rf = 0; rf < 2; rf++)
        #pragma unroll
        for (int fr = 0; fr < 3; fr++) {
            int n = cg * 3 + fr;
            int m = n >> 2, colm = (n & 3) * 16 + c;
            const float* bias = (m == 0) ? bq : (m == 1) ? bk : bv;
            float bv_ = bias[colm];
            if (m == 2) {
                u16x4 pk;
                #pragma unroll
                for (int j = 0; j < 4; j++) pk[j] = (unsigned short)f2bf(acc[rf][fr][j] + bv_);
                int srw = sbase + rf * 16 + 4 * g;
                *(u16x4*)(Vt + (size_t)bb * DK * SEQ + (size_t)colm * SEQ + srw) = pk;
            } else {
                #pragma unroll
                for (int j = 0; j < 4; j++) {
                    int row = r0 + rf * 16 + 4 * g + j;
                    float s = acc[rf][fr][j] + bv_;
                    if (m == 0) Q[(size_t)row * DK + colm] = f2bf(s * QSCALE);
                    else        K[(size_t)row * DK + colm] = f2bf(s);
                }
            }
        }
}

// ---------------- flash attention v11: R7 structure + XCD-pinned batches -----------
// bid & 7 = batch -> all blocks of batch b land on XCD b (round-robin dispatch),
// so K_b/V_b/Q_b (768 KB) stay resident in that XCD's 4 MiB L2.
__global__ __launch_bounds__(256) void attn_kernel(
    const short* __restrict__ Q, const short* __restrict__ K_, const short* __restrict__ Vt,
    const int* __restrict__ lengths, float* __restrict__ out) {
    __shared__ float macc[4][32][66];          // merge buffer (33.8 KiB)
    __shared__ float ll[4][32];
    short* plds = (short*)&macc[0][0][0];      // aliased P-transpose region (17.9 KiB)

    int bid = blockIdx.x;
    int b = bid & 7;                           // XCD-pinned batch
    int qt = 63 - (bid >> 3);                  // heavy tiles dispatch first
    int len = lengths[b];
    int qbase = qt * 32;
    int t = threadIdx.x;
    int w = t >> 6, lane = t & 63;
    int g = lane >> 4, c = lane & 15;

    if (qbase >= len) {                        // fully padded tile -> zeros
        int row = t >> 3, seg = t & 7;
        float* op = out + ((size_t)b * SEQ + qbase + row) * DK + seg * 8;
        #pragma unroll
        for (int i = 0; i < 8; i++) op[i] = 0.f;
        return;
    }

    int kend = min(len, qbase + 32);
    int ntiles = (kend + 63) >> 6;
    const short* Qb = Q + ((size_t)b * SEQ + qbase) * DK;
    const short* Kb = K_ + (size_t)b * SEQ * DK;
    const short* Vb = Vt + (size_t)b * DK * SEQ;

    bf16x8 qa[2][2];
    #pragma unroll
    for (int f = 0; f < 2; f++)
        #pragma unroll
        for (int kh = 0; kh < 2; kh++)
            qa[f][kh] = *(const bf16x8*)(Qb + (f * 16 + c) * DK + kh * 32 + g * 8);

    int rowcap[2][4];
    #pragma unroll
    for (int f = 0; f < 2; f++)
        #pragma unroll
        for (int j = 0; j < 4; j++)
            rowcap[f][j] = min(qbase + f * 16 + 4 * g + j, len - 1);

    f32x4 z = {0.f, 0.f, 0.f, 0.f};
    f32x4 acc[2][4];
    float l_r[2][4];
    #pragma unroll
    for (int f = 0; f < 2; f++) {
        #pragma unroll
        for (int n = 0; n < 4; n++) acc[f][n] = z;
        #pragma unroll
        for (int j = 0; j < 4; j++) l_r[f][j] = 0.f;
    }

    short* pldsw = plds + w * 2240;            // [2][16][70] shorts per wave

    // preload first half (keys kb..kb+31) of this wave's first tile
    bf16x8 kh0[2][2];
    if (w < ntiles) {
        #pragma unroll
        for (int kt = 0; kt < 2; kt++) {
            const short* kp = Kb + (size_t)(w * 64 + kt * 16 + c) * DK + g * 8;
            kh0[kt][0] = *(const bf16x8*)kp;
            kh0[kt][1] = *(const bf16x8*)(kp + 32);
        }
    }

    for (int tt = w; tt < ntiles; tt += 4) {
        int kb = tt * 64;
        // second-half K loads issued first (independent), then half-0 MFMAs
        bf16x8 kh1[2][2];
        #pragma unroll
        for (int kt = 0; kt < 2; kt++) {
            const short* kp = Kb + (size_t)(kb + 32 + kt * 16 + c) * DK + g * 8;
            kh1[kt][0] = *(const bf16x8*)kp;
            kh1[kt][1] = *(const bf16x8*)(kp + 32);
        }
        f32x4 sf[2][4];
        #pragma unroll
        for (int kt = 0; kt < 2; kt++)
            #pragma unroll
            for (int f = 0; f < 2; f++) {
                f32x4 t0 = __builtin_amdgcn_mfma_f32_16x16x32_bf16(qa[f][0], kh0[kt][0], z, 0, 0, 0);
                sf[f][kt] = __builtin_amdgcn_mfma_f32_16x16x32_bf16(qa[f][1], kh0[kt][1], t0, 0, 0, 0);
            }
        // prefetch next tile's half-0 (hides latency under softmax/PV)
        if (tt + 4 < ntiles) {
            #pragma unroll
            for (int kt = 0; kt < 2; kt++) {
                const short* kp = Kb + (size_t)((tt + 4) * 64 + kt * 16 + c) * DK + g * 8;
                kh0[kt][0] = *(const bf16x8*)kp;
                kh0[kt][1] = *(const bf16x8*)(kp + 32);
            }
        }
        // V loads (independent of everything until PV)
        bf16x8 vr[4][2];
        #pragma unroll
        for (int n = 0; n < 4; n++) {
            const short* vp = Vb + (size_t)(n * 16 + c) * SEQ + kb + g * 8;
            vr[n][0] = *(const bf16x8*)vp;
            vr[n][1] = *(const bf16x8*)(vp + 32);
        }
        // half-1 MFMAs
        #pragma unroll
        for (int kt = 0; kt < 2; kt++)
            #pragma unroll
            for (int f = 0; f < 2; f++) {
                f32x4 t0 = __builtin_amdgcn_mfma_f32_16x16x32_bf16(qa[f][0], kh1[kt][0], z, 0, 0, 0);
                sf[f][kt + 2] = __builtin_amdgcn_mfma_f32_16x16x32_bf16(qa[f][1], kh1[kt][1], t0, 0, 0, 0);
            }
        // mask + exp2 + per-lane l accumulation (no cross-lane ops)
        #pragma unroll
        for (int kt = 0; kt < 4; kt++) {
            int key = kb + kt * 16 + c;
            #pragma unroll
            for (int f = 0; f < 2; f++)
                #pragma unroll
                for (int j = 0; j < 4; j++) {
                    float s = (key > rowcap[f][j]) ? -1e30f : sf[f][kt][j];
                    float p = exp2f(s - FIXMAX2);
                    sf[f][kt][j] = p;
                    l_r[f][j] += p;
                }
        }
        // P: D-layout -> LDS -> A-layout (wave-private lockstep, no barrier)
        #pragma unroll
        for (int f = 0; f < 2; f++)
            #pragma unroll
            for (int kt = 0; kt < 4; kt++)
                #pragma unroll
                for (int j = 0; j < 4; j++)
                    pldsw[f * 1120 + (4 * g + j) * 70 + kt * 16 + c] = f2bf(sf[f][kt][j]);
        #pragma unroll
        for (int f = 0; f < 2; f++) {
            bf16x8 pa0 = *(const bf16x8*)(pldsw + f * 1120 + c * 70 + g * 8);
            bf16x8 pa1 = *(const bf16x8*)(pldsw + f * 1120 + c * 70 + 32 + g * 8);
            #pragma unroll
            for (int n = 0; n < 4; n++) {
                acc[f][n] = __builtin_amdgcn_mfma_f32_16x16x32_bf16(pa0, vr[n][0], acc[f][n], 0, 0, 0);
                acc[f][n] = __builtin_amdgcn_mfma_f32_16x16x32_bf16(pa1, vr[n][1], acc[f][n], 0, 0, 0);
            }
        }
    }

    // one-time l reduction across the 16 lanes holding each row
    #pragma unroll
    for (int d = 1; d < 16; d <<= 1)
        #pragma unroll
        for (int f = 0; f < 2; f++)
            #pragma unroll
            for (int j = 0; j < 4; j++) l_r[f][j] += __shfl_xor(l_r[f][j], d);

    __syncthreads();   // plds lifetime over -> reuse as macc
    #pragma unroll
    for (int f = 0; f < 2; f++)
        #pragma unroll
        for (int n = 0; n < 4; n++)
            #pragma unroll
            for (int j = 0; j < 4; j++)
                macc[w][f * 16 + 4 * g + j][n * 16 + c] = acc[f][n][j];
    if (c == 0) {
        #pragma unroll
        for (int f = 0; f < 2; f++)
            #pragma unroll
            for (int j = 0; j < 4; j++)
                ll[w][f * 16 + 4 * g + j] = l_r[f][j];
    }
    __syncthreads();
    // merge: plain sums (all waves share the same fixed max)
    {
        int row = t >> 3, seg = t & 7;
        int r = qbase + row;
        float* op = out + ((size_t)b * SEQ + r) * DK + seg * 8;
        float o[8];
        #pragma unroll
        for (int i = 0; i < 8; i++) o[i] = 0.f;
        if (r < len) {
            float L = ll[0][row] + ll[1][row] + ll[2][row] + ll[3][row];
            #pragma unroll
            for (int wv = 0; wv < 4; wv++)
                #pragma unroll
                for (int i = 0; i < 8; i++) o[i] += macc[wv][row][seg * 8 + i];
            float inv = 1.f / L;
            #pragma unroll
            for (int i = 0; i < 8; i++) o[i] *= inv;
        }
        #pragma unroll
        for (int i = 0; i < 8; i++) op[i] = o[i];
    }
}

extern "C" void kernel_launch(void* const* d_in, const int* in_sizes, int n_in,
                              void* d_out, int out_size, void* d_ws, size_t ws_size,
                              hipStream_t stream) {
    const float* x  = (const float*)d_in[0];
    const unsigned* mask = (const unsigned*)d_in[1];
    const float* Wq = (const float*)d_in[2];
    const float* bq = (const float*)d_in[3];
    const float* Wk = (const float*)d_in[4];
    const float* bk = (const float*)d_in[5];
    const float* Wv = (const float*)d_in[6];
    const float* bv = (const float*)d_in[7];
    float* out = (float*)d_out;

    char* ws = (char*)d_ws;
    int*   lengths = (int*)ws;                          // 256 B
    short* Wp = (short*)(ws + 256);                     // 384 KiB (Wp2 layout)
    short* Q  = (short*)(ws + 393472);                  // 2 MiB
    short* K  = (short*)(ws + 2490624);                 // 2 MiB
    short* Vt = (short*)(ws + 4587776);                 // 2 MiB

    hipLaunchKernelGGL(prep_kernel, dim3(776), dim3(256), 0, stream, mask, Wq, Wk, Wv, lengths, Wp);
    hipLaunchKernelGGL(qkv_kernel, dim3(512), dim3(256), 0, stream,
                       x, bq, bk, bv, Wp, Q, K, Vt);
    hipLaunchKernelGGL(attn_kernel, dim3(NB * 64), dim3(256), 0, stream,
                       Q, K, Vt, lengths, out);
}

// Round 12
// 54.776 us; speedup vs baseline: 1.2813x; 1.0599x over previous
//
#include <hip/hip_runtime.h>
#include <hip/hip_bf16.h>

#define NB 8
#define SEQ 2048
#define HD 1024
#define DK 64

// exp2-domain constants: Q pre-scaled by 0.125/ln2, fixed softmax base 8/ln2
#define QSCALE 0.1803368801111244f
#define FIXMAX2 11.541560327111708f

typedef __attribute__((ext_vector_type(4))) float f32x4;
typedef __attribute__((ext_vector_type(8))) short bf16x8;
typedef __attribute__((ext_vector_type(4))) unsigned short u16x4;

// raw barrier: LDS-only fence (lgkmcnt), NO vmcnt drain -> global loads stay in flight
#define LDS_BARRIER() asm volatile("s_waitcnt lgkmcnt(0)\n\ts_barrier" ::: "memory")

__device__ __forceinline__ short f2bf(float f) {
    union { float f; unsigned u; } v; v.f = f;
    unsigned r = v.u + 0x7fffu + ((v.u >> 16) & 1u);
    return (short)(r >> 16);
}
__device__ __forceinline__ bf16x8 pack8(f32x4 v0, f32x4 v1) {
    union { bf16x8 v; __hip_bfloat162 h[4]; } u;
    u.h[0] = __float22bfloat162_rn(make_float2(v0[0], v0[1]));
    u.h[1] = __float22bfloat162_rn(make_float2(v0[2], v0[3]));
    u.h[2] = __float22bfloat162_rn(make_float2(v1[0], v1[1]));
    u.h[3] = __float22bfloat162_rn(make_float2(v1[2], v1[3]));
    return u.v;
}

// ---------------- prep: W pack (blocks 0..767) + lengths (768..775) ----------------
// Wp2[(((kbg*4+cg)*2+kh)*3+fr)*512 + lane*8 + j] = W_m[k][colm]
__global__ void prep_kernel(const unsigned* __restrict__ mask,
                            const float* __restrict__ Wq, const float* __restrict__ Wk,
                            const float* __restrict__ Wv,
                            int* __restrict__ lengths, short* __restrict__ Wp) {
    if (blockIdx.x < 768) {
        int idx = blockIdx.x * 256 + threadIdx.x;     // 0..196607
        int j = idx & 7, lane = (idx >> 3) & 63;
        int slot = idx >> 9;                          // 0..383
        int fr = slot % 3, q2 = slot / 3;
        int kh = q2 & 1, cg = (q2 >> 1) & 3, kbg = q2 >> 3;
        int g = lane >> 4, c = lane & 15;
        int n = cg * 3 + fr;
        int m = n >> 2, colm = (n & 3) * 16 + c;
        int k = kbg * 64 + kh * 32 + g * 8 + j;
        const float* W = (m == 0) ? Wq : (m == 1) ? Wk : Wv;
        Wp[idx] = f2bf(W[(size_t)k * DK + colm]);
        return;
    }
    __shared__ int sdet;
    __shared__ int scnt;
    int b = blockIdx.x - 768, t = threadIdx.x;
    if (t == 0) { sdet = 0; scnt = 0; }
    __syncthreads();
    int det = 0;
    for (int i = t; i < 4096; i += 256) {
        unsigned w = mask[i];
        if (w > 1u && w != 0x3F800000u) det = 1;
    }
    if (det) atomicOr(&sdet, 1);
    __syncthreads();
    int cnt = 0;
    if (sdet) {
        const unsigned char* m8 = (const unsigned char*)mask;
        for (int s = t; s < SEQ; s += 256) cnt += (m8[b * SEQ + s] == 0) ? 1 : 0;
    } else {
        for (int s = t; s < SEQ; s += 256) cnt += (mask[b * SEQ + s] == 0u) ? 1 : 0;
    }
    atomicAdd(&scnt, cnt);
    __syncthreads();
    if (t == 0) lengths[b] = scnt;
}

// ---------------- QKV v11: bf16-in-LDS dbuf GEMM, counted-vmcnt pipeline -----------
__global__ __launch_bounds__(256) void qkv_kernel(
    const float* __restrict__ x,
    const float* __restrict__ bq, const float* __restrict__ bk, const float* __restrict__ bv,
    const short* __restrict__ Wp,
    short* __restrict__ Q, short* __restrict__ K, short* __restrict__ Vt) {
    __shared__ short xs[2][32][64];    // 8 KiB bf16, granule-swizzled
    int t = threadIdx.x;
    int cg = t >> 6, lane = t & 63;
    int g = lane >> 4, c = lane & 15;
    int r0 = blockIdx.x * 32;
    int bb = r0 >> 11, sbase = r0 & (SEQ - 1);

    int srow = t >> 3, ch = t & 7;
    const float* xsrc = x + (size_t)(r0 + srow) * HD + ch * 8;
    short* wbase = &xs[0][0][0];
    int wo = srow * 64 + ((ch ^ (srow & 7)) << 3);    // shorts

    const short* wpw = Wp + (size_t)cg * 3072 + (size_t)lane * 8;

    f32x4 z = {0.f, 0.f, 0.f, 0.f};
    f32x4 acc[2][3];
    #pragma unroll
    for (int rf = 0; rf < 2; rf++)
        #pragma unroll
        for (int fr = 0; fr < 3; fr++) acc[rf][fr] = z;

    // prologue: stage step 0 (convert at write), preload B step 0, issue x step 1
    {
        f32x4 x0 = *(const f32x4*)xsrc;
        f32x4 x1 = *(const f32x4*)(xsrc + 4);
        *(bf16x8*)(wbase + wo) = pack8(x0, x1);
    }
    bf16x8 Bc[2][3];
    #pragma unroll
    for (int kh = 0; kh < 2; kh++)
        #pragma unroll
        for (int fr = 0; fr < 3; fr++)
            Bc[kh][fr] = *(const bf16x8*)(wpw + kh * 1536 + fr * 512);
    f32x4 nxA0 = *(const f32x4*)(xsrc + 64);
    f32x4 nxA1 = *(const f32x4*)(xsrc + 68);
    LDS_BARRIER();

    const short* rbase0 = &xs[0][0][0] + c * 64;   // + cur*2048 + rf*1024 + chunk*8
    #pragma unroll
    for (int kbg = 0; kbg < 16; kbg++) {
        int cur = kbg & 1;
        // issue x loads for kbg+2 (2-deep) and B loads for kbg+1 (1-deep) FIRST
        f32x4 nxB0, nxB1;
        bf16x8 Bn[2][3];
        if (kbg < 14) {
            const float* p = xsrc + (kbg + 2) * 64;
            nxB0 = *(const f32x4*)p;
            nxB1 = *(const f32x4*)(p + 4);
        }
        if (kbg < 15) {
            #pragma unroll
            for (int kh = 0; kh < 2; kh++)
                #pragma unroll
                for (int fr = 0; fr < 3; fr++)
                    Bn[kh][fr] = *(const bf16x8*)(wpw + (kbg + 1) * 12288 + kh * 1536 + fr * 512);
        }
        // A frags: direct bf16 ds_read_b128 (no conversion)
        bf16x8 Af[2][2];
        #pragma unroll
        for (int rf = 0; rf < 2; rf++)
            #pragma unroll
            for (int kh = 0; kh < 2; kh++)
                Af[rf][kh] = *(const bf16x8*)(rbase0 + cur * 2048 + rf * 1024
                                              + (((kh * 4 + g) ^ (c & 7)) << 3));
        #pragma unroll
        for (int kh = 0; kh < 2; kh++)
            #pragma unroll
            for (int fr = 0; fr < 3; fr++)
                #pragma unroll
                for (int rf = 0; rf < 2; rf++)
                    acc[rf][fr] = __builtin_amdgcn_mfma_f32_16x16x32_bf16(Af[rf][kh], Bc[kh][fr], acc[rf][fr], 0, 0, 0);
        if (kbg < 15) {
            // counted vmcnt wait lands here (nxA issued 2 steps ago)
            *(bf16x8*)(wbase + (cur ^ 1) * 2048 + wo) = pack8(nxA0, nxA1);
            #pragma unroll
            for (int kh = 0; kh < 2; kh++)
                #pragma unroll
                for (int fr = 0; fr < 3; fr++) Bc[kh][fr] = Bn[kh][fr];
        }
        if (kbg < 14) { nxA0 = nxB0; nxA1 = nxB1; }
        LDS_BARRIER();
    }

    // epilogue
    #pragma unroll
    for (int rf = 0; rf < 2; rf++)
        #pragma unroll
        for (int fr = 0; fr < 3; fr++) {
            int n = cg * 3 + fr;
            int m = n >> 2, colm = (n & 3) * 16 + c;
            const float* bias = (m == 0) ? bq : (m == 1) ? bk : bv;
            float bv_ = bias[colm];
            if (m == 2) {
                u16x4 pk;
                #pragma unroll
                for (int j = 0; j < 4; j++) pk[j] = (unsigned short)f2bf(acc[rf][fr][j] + bv_);
                int srw = sbase + rf * 16 + 4 * g;
                *(u16x4*)(Vt + (size_t)bb * DK * SEQ + (size_t)colm * SEQ + srw) = pk;
            } else {
                #pragma unroll
                for (int j = 0; j < 4; j++) {
                    int row = r0 + rf * 16 + 4 * g + j;
                    float s = acc[rf][fr][j] + bv_;
                    if (m == 0) Q[(size_t)row * DK + colm] = f2bf(s * QSCALE);
                    else        K[(size_t)row * DK + colm] = f2bf(s);
                }
            }
        }
}

// ---------------- flash attention v12: 8 waves/block, XCD-pinned batches -----------
// Block = one 32-row q-tile, 8 waves on interleaved 64-key stripes (tt += 8).
// Doubles waves/CU vs v11 (16 waves/CU at 2 blocks/CU) without extra K/V traffic.
__global__ __launch_bounds__(512) void attn_kernel(
    const short* __restrict__ Q, const short* __restrict__ K_, const short* __restrict__ Vt,
    const int* __restrict__ lengths, float* __restrict__ out) {
    __shared__ float macc[8][32][66];          // merge buffer (67.6 KiB)
    __shared__ float ll[8][32];
    short* plds = (short*)&macc[0][0][0];      // aliased P-transpose region (35.8 KiB)

    int bid = blockIdx.x;
    int b = bid & 7;                           // XCD-pinned batch
    int qt = 63 - (bid >> 3);                  // heavy tiles dispatch first
    int len = lengths[b];
    int qbase = qt * 32;
    int t = threadIdx.x;
    int w = t >> 6, lane = t & 63;
    int g = lane >> 4, c = lane & 15;

    if (qbase >= len) {                        // fully padded tile -> zeros
        int row = t >> 4, col0 = (t & 15) * 4;
        f32x4 zz = {0.f, 0.f, 0.f, 0.f};
        *(f32x4*)(out + ((size_t)b * SEQ + qbase + row) * DK + col0) = zz;
        return;
    }

    int kend = min(len, qbase + 32);
    int ntiles = (kend + 63) >> 6;
    const short* Qb = Q + ((size_t)b * SEQ + qbase) * DK;
    const short* Kb = K_ + (size_t)b * SEQ * DK;
    const short* Vb = Vt + (size_t)b * DK * SEQ;

    bf16x8 qa[2][2];
    #pragma unroll
    for (int f = 0; f < 2; f++)
        #pragma unroll
        for (int kh = 0; kh < 2; kh++)
            qa[f][kh] = *(const bf16x8*)(Qb + (f * 16 + c) * DK + kh * 32 + g * 8);

    int rowcap[2][4];
    #pragma unroll
    for (int f = 0; f < 2; f++)
        #pragma unroll
        for (int j = 0; j < 4; j++)
            rowcap[f][j] = min(qbase + f * 16 + 4 * g + j, len - 1);

    f32x4 z = {0.f, 0.f, 0.f, 0.f};
    f32x4 acc[2][4];
    float l_r[2][4];
    #pragma unroll
    for (int f = 0; f < 2; f++) {
        #pragma unroll
        for (int n = 0; n < 4; n++) acc[f][n] = z;
        #pragma unroll
        for (int j = 0; j < 4; j++) l_r[f][j] = 0.f;
    }

    short* pldsw = plds + w * 2240;            // [2][16][70] shorts per wave

    // preload first half (keys kb..kb+31) of this wave's first tile
    bf16x8 kh0[2][2];
    if (w < ntiles) {
        #pragma unroll
        for (int kt = 0; kt < 2; kt++) {
            const short* kp = Kb + (size_t)(w * 64 + kt * 16 + c) * DK + g * 8;
            kh0[kt][0] = *(const bf16x8*)kp;
            kh0[kt][1] = *(const bf16x8*)(kp + 32);
        }
    }

    for (int tt = w; tt < ntiles; tt += 8) {
        int kb = tt * 64;
        // second-half K loads issued first (independent), then half-0 MFMAs
        bf16x8 kh1[2][2];
        #pragma unroll
        for (int kt = 0; kt < 2; kt++) {
            const short* kp = Kb + (size_t)(kb + 32 + kt * 16 + c) * DK + g * 8;
            kh1[kt][0] = *(const bf16x8*)kp;
            kh1[kt][1] = *(const bf16x8*)(kp + 32);
        }
        f32x4 sf[2][4];
        #pragma unroll
        for (int kt = 0; kt < 2; kt++)
            #pragma unroll
            for (int f = 0; f < 2; f++) {
                f32x4 t0 = __builtin_amdgcn_mfma_f32_16x16x32_bf16(qa[f][0], kh0[kt][0], z, 0, 0, 0);
                sf[f][kt] = __builtin_amdgcn_mfma_f32_16x16x32_bf16(qa[f][1], kh0[kt][1], t0, 0, 0, 0);
            }
        // prefetch next tile's half-0 (hides latency under softmax/PV)
        if (tt + 8 < ntiles) {
            #pragma unroll
            for (int kt = 0; kt < 2; kt++) {
                const short* kp = Kb + (size_t)((tt + 8) * 64 + kt * 16 + c) * DK + g * 8;
                kh0[kt][0] = *(const bf16x8*)kp;
                kh0[kt][1] = *(const bf16x8*)(kp + 32);
            }
        }
        // V loads (independent of everything until PV)
        bf16x8 vr[4][2];
        #pragma unroll
        for (int n = 0; n < 4; n++) {
            const short* vp = Vb + (size_t)(n * 16 + c) * SEQ + kb + g * 8;
            vr[n][0] = *(const bf16x8*)vp;
            vr[n][1] = *(const bf16x8*)(vp + 32);
        }
        // half-1 MFMAs
        #pragma unroll
        for (int kt = 0; kt < 2; kt++)
            #pragma unroll
            for (int f = 0; f < 2; f++) {
                f32x4 t0 = __builtin_amdgcn_mfma_f32_16x16x32_bf16(qa[f][0], kh1[kt][0], z, 0, 0, 0);
                sf[f][kt + 2] = __builtin_amdgcn_mfma_f32_16x16x32_bf16(qa[f][1], kh1[kt][1], t0, 0, 0, 0);
            }
        // mask + exp2 + per-lane l accumulation (no cross-lane ops)
        #pragma unroll
        for (int kt = 0; kt < 4; kt++) {
            int key = kb + kt * 16 + c;
            #pragma unroll
            for (int f = 0; f < 2; f++)
                #pragma unroll
                for (int j = 0; j < 4; j++) {
                    float s = (key > rowcap[f][j]) ? -1e30f : sf[f][kt][j];
                    float p = exp2f(s - FIXMAX2);
                    sf[f][kt][j] = p;
                    l_r[f][j] += p;
                }
        }
        // P: D-layout -> LDS -> A-layout (wave-private lockstep, no barrier)
        #pragma unroll
        for (int f = 0; f < 2; f++)
            #pragma unroll
            for (int kt = 0; kt < 4; kt++)
                #pragma unroll
                for (int j = 0; j < 4; j++)
                    pldsw[f * 1120 + (4 * g + j) * 70 + kt * 16 + c] = f2bf(sf[f][kt][j]);
        #pragma unroll
        for (int f = 0; f < 2; f++) {
            bf16x8 pa0 = *(const bf16x8*)(pldsw + f * 1120 + c * 70 + g * 8);
            bf16x8 pa1 = *(const bf16x8*)(pldsw + f * 1120 + c * 70 + 32 + g * 8);
            #pragma unroll
            for (int n = 0; n < 4; n++) {
                acc[f][n] = __builtin_amdgcn_mfma_f32_16x16x32_bf16(pa0, vr[n][0], acc[f][n], 0, 0, 0);
                acc[f][n] = __builtin_amdgcn_mfma_f32_16x16x32_bf16(pa1, vr[n][1], acc[f][n], 0, 0, 0);
            }
        }
    }

    // one-time l reduction across the 16 lanes holding each row
    #pragma unroll
    for (int d = 1; d < 16; d <<= 1)
        #pragma unroll
        for (int f = 0; f < 2; f++)
            #pragma unroll
            for (int j = 0; j < 4; j++) l_r[f][j] += __shfl_xor(l_r[f][j], d);

    __syncthreads();   // plds lifetime over -> reuse as macc
    #pragma unroll
    for (int f = 0; f < 2; f++)
        #pragma unroll
        for (int n = 0; n < 4; n++)
            #pragma unroll
            for (int j = 0; j < 4; j++)
                macc[w][f * 16 + 4 * g + j][n * 16 + c] = acc[f][n][j];
    if (c == 0) {
        #pragma unroll
        for (int f = 0; f < 2; f++)
            #pragma unroll
            for (int j = 0; j < 4; j++)
                ll[w][f * 16 + 4 * g + j] = l_r[f][j];
    }
    __syncthreads();
    // merge: plain sums (all waves share the same fixed max)
    {
        int row = t >> 4, seg = t & 15;
        int r = qbase + row;
        float* op = out + ((size_t)b * SEQ + r) * DK + seg * 4;
        float o[4] = {0.f, 0.f, 0.f, 0.f};
        if (r < len) {
            float L = 0.f;
            #pragma unroll
            for (int wv = 0; wv < 8; wv++) L += ll[wv][row];
            #pragma unroll
            for (int wv = 0; wv < 8; wv++)
                #pragma unroll
                for (int i = 0; i < 4; i++) o[i] += macc[wv][row][seg * 4 + i];
            float inv = 1.f / L;
            #pragma unroll
            for (int i = 0; i < 4; i++) o[i] *= inv;
        }
        #pragma unroll
        for (int i = 0; i < 4; i++) op[i] = o[i];
    }
}

extern "C" void kernel_launch(void* const* d_in, const int* in_sizes, int n_in,
                              void* d_out, int out_size, void* d_ws, size_t ws_size,
                              hipStream_t stream) {
    const float* x  = (const float*)d_in[0];
    const unsigned* mask = (const unsigned*)d_in[1];
    const float* Wq = (const float*)d_in[2];
    const float* bq = (const float*)d_in[3];
    const float* Wk = (const float*)d_in[4];
    const float* bk = (const float*)d_in[5];
    const float* Wv = (const float*)d_in[6];
    const float* bv = (const float*)d_in[7];
    float* out = (float*)d_out;

    char* ws = (char*)d_ws;
    int*   lengths = (int*)ws;                          // 256 B
    short* Wp = (short*)(ws + 256);                     // 384 KiB (Wp2 layout)
    short* Q  = (short*)(ws + 393472);                  // 2 MiB
    short* K  = (short*)(ws + 2490624);                 // 2 MiB
    short* Vt = (short*)(ws + 4587776);                 // 2 MiB

    hipLaunchKernelGGL(prep_kernel, dim3(776), dim3(256), 0, stream, mask, Wq, Wk, Wv, lengths, Wp);
    hipLaunchKernelGGL(qkv_kernel, dim3(512), dim3(256), 0, stream,
                       x, bq, bk, bv, Wp, Q, K, Vt);
    hipLaunchKernelGGL(attn_kernel, dim3(NB * 64), dim3(512), 0, stream,
                       Q, K, Vt, lengths, out);
}